// Round 15
// baseline (321.322 us; speedup 1.0000x reference)
//
#include <hip/hip_runtime.h>
#include <hip/hip_fp16.h>
#include <math.h>

// ---------------------------------------------------------------------------
// AttentionZP: swishmax attention, B=2, H=8, T=1024, A=64, C=256, Q=K=2048.
//
// Round 14 -> 15:
//  * proj/final reverted to r10 64x128 tiles (64x64 retile cost 5.5us: 2x
//    staging bytes/FLOP).
//  * flash_attn SPLIT-K: grid 1024, each block does a 1024-key half (16
//    tiles, identical inner code; 3 blocks/CU by LDS vs 2 before). Block
//    epilogue is unchanged math (P_b = acc*sfix/(l*sfix+1)) written to a
//    per-half partial buffer + per-q scalars L_b = l*sfix, M_b = m_true.
//  * combine_halves: out = sum(P_b*(L_b+1)*e^{M_b-M}) /
//    (sum(L_b*e^{M_b-M}) + 1), in-place over P0 (= vs_c), ~48MB HBM.
//  Aliasing: P0/vs_c <- qtok region (dead after proj); P1 <- [ktok_f..vdT)
//  16MB (dead after kv_gemm); kvT <- ktok region as before.
// ---------------------------------------------------------------------------

typedef _Float16 f16;
typedef _Float16 f16x4 __attribute__((ext_vector_type(4)));
typedef _Float16 f16x8 __attribute__((ext_vector_type(8)));
typedef short s16x4 __attribute__((ext_vector_type(4)));
typedef short bf16x8 __attribute__((ext_vector_type(8)));
typedef float f32x4 __attribute__((ext_vector_type(4)));

#define MFMA_F16(a, b, c) __builtin_amdgcn_mfma_f32_16x16x32_f16(a, b, c, 0, 0, 0)
#define MFMA_BF16(a, b, c) __builtin_amdgcn_mfma_f32_16x16x32_bf16(a, b, c, 0, 0, 0)

__device__ __forceinline__ void g2lds16(const void* g, void* l) {
  // async global->LDS, 16B/lane; LDS dest is wave-uniform base + lane*16
  __builtin_amdgcn_global_load_lds((__attribute__((address_space(1))) void*)g,
                                   (__attribute__((address_space(3))) void*)l, 16, 0, 0);
}

__device__ __forceinline__ short f32_bf16(float x) {
  union { float f; unsigned u; } v; v.f = x;
  unsigned r = v.u + 0x7FFFu + ((v.u >> 16) & 1u);  // RTN-even
  return (short)(r >> 16);
}
__device__ __forceinline__ float bf16_f32(short h) {
  union { unsigned u; float f; } v; v.u = ((unsigned)(unsigned short)h) << 16;
  return v.f;
}

// --------------------------- prep: elementwise split (both tokens) ----------
__global__ __launch_bounds__(256) void ew_split2(const float* __restrict__ qin,
                                                 const float* __restrict__ kin,
                                                 short* __restrict__ qhi,
                                                 short* __restrict__ qlo,
                                                 short* __restrict__ khi,
                                                 short* __restrict__ klo,
                                                 f16* __restrict__ kf) {
  int i = blockIdx.x * 256 + threadIdx.x;  // 0 .. 2M-1 quads (grid exact)
  const bool isK = i >= 1048576;
  const int j = isK ? i - 1048576 : i;
  const float* in = isK ? kin : qin;
  f32x4 v = ((const f32x4*)in)[j];
  s16x4 h, l;
  f16x4 f;
#pragma unroll
  for (int e = 0; e < 4; e++) {
    short he = f32_bf16(v[e]);
    h[e] = he;
    l[e] = f32_bf16(v[e] - bf16_f32(he));
    f[e] = (f16)v[e];
  }
  if (isK) {
    ((s16x4*)khi)[j] = h;
    ((s16x4*)klo)[j] = l;
    ((f16x4*)kf)[j] = f;
  } else {
    ((s16x4*)qhi)[j] = h;
    ((s16x4*)qlo)[j] = l;
  }
}

// --------------------------- prep: fused transpose (+split) -----------------
// One dispatch for all four weight transposes. Block decode:
//   [0,128)    qdw  [8][1024][64] -> wqT hi/lo  [512][1024]
//   [128,256)  kdw  -> wkT hi/lo
//   [256,768)  vdw  [8][1024][256] -> vdT f16 [2048][1024]
//   [768,1280) vup  [2048][1024]   -> vuT f16 [1024][2048]
__global__ __launch_bounds__(256) void transpose_all(
    const float* __restrict__ qdw, const float* __restrict__ kdw,
    const float* __restrict__ vdw, const float* __restrict__ vup,
    short* __restrict__ wqT_hi, short* __restrict__ wqT_lo,
    short* __restrict__ wkT_hi, short* __restrict__ wkT_lo,
    f16* __restrict__ vdT, f16* __restrict__ vuT) {
  __shared__ float t[64][65];
  int idx = blockIdx.x;
  const float* in;
  short *bhi = nullptr, *blo = nullptr;
  f16* fo = nullptr;
  int R, C, cb, rb;
  size_t batch;
  if (idx < 256) {
    bool isQ = idx < 128;
    int i = isQ ? idx : idx - 128;
    in = isQ ? qdw : kdw;
    bhi = isQ ? wqT_hi : wkT_hi;
    blo = isQ ? wqT_lo : wkT_lo;
    R = 1024; C = 64; cb = 0; rb = (i & 15) * 64;
    batch = (size_t)(i >> 4) * R * C;
  } else if (idx < 768) {
    int i = idx - 256;
    in = vdw; fo = vdT;
    R = 1024; C = 256; cb = (i & 3) * 64; rb = ((i >> 2) & 15) * 64;
    batch = (size_t)(i >> 6) * R * C;
  } else {
    int i = idx - 768;
    in = vup; fo = vuT;
    R = 2048; C = 1024; cb = (i & 15) * 64; rb = (i >> 4) * 64;
    batch = 0;
  }
  int tid = threadIdx.x;
#pragma unroll
  for (int i = 0; i < 4; i++) {
    int r = (tid >> 4) + i * 16, c4 = (tid & 15) * 4;
    f32x4 v = *(const f32x4*)(in + batch + (size_t)(rb + r) * C + cb + c4);
    t[r][c4] = v[0]; t[r][c4 + 1] = v[1]; t[r][c4 + 2] = v[2]; t[r][c4 + 3] = v[3];
  }
  __syncthreads();
#pragma unroll
  for (int i = 0; i < 4; i++) {
    int c = (tid >> 4) + i * 16, r4 = (tid & 15) * 4;
    float v0 = t[r4][c], v1 = t[r4 + 1][c], v2 = t[r4 + 2][c], v3 = t[r4 + 3][c];
    size_t o = batch + (size_t)(cb + c) * R + rb + r4;
    if (bhi) {
      s16x4 h = {f32_bf16(v0), f32_bf16(v1), f32_bf16(v2), f32_bf16(v3)};
      *(s16x4*)(bhi + o) = h;
      s16x4 l = {f32_bf16(v0 - bf16_f32(h[0])), f32_bf16(v1 - bf16_f32(h[1])),
                 f32_bf16(v2 - bf16_f32(h[2])), f32_bf16(v3 - bf16_f32(h[3]))};
      *(s16x4*)(blo + o) = l;
    }
    if (fo) {
      f16x4 fv = {(f16)v0, (f16)v1, (f16)v2, (f16)v3};
      *(f16x4*)(fo + o) = fv;
    }
  }
}

// --------------------------- split-bf16 projection GEMM ----------------------
// M=4096(b,row) K=1024(t) N=512(h,a). Tile 64x128, 4 waves (2x2, 32x64 each).
// out: {q,k}_split[bh][row][ hi(64) | lo(64) ]  (bf16)  [r10 version]
__global__ __launch_bounds__(256, 3) void proj_gemm(
    const short* __restrict__ qtok_hi, const short* __restrict__ qtok_lo,
    const short* __restrict__ ktok_hi, const short* __restrict__ ktok_lo,
    const short* __restrict__ wqT_hi, const short* __restrict__ wqT_lo,
    const short* __restrict__ wkT_hi, const short* __restrict__ wkT_lo,
    const float* __restrict__ bias, short* __restrict__ q_split,
    short* __restrict__ k_split) {
  const bool isQ = (blockIdx.z == 0);
  const short* Ahi = isQ ? qtok_hi : ktok_hi;
  const short* Alo = isQ ? qtok_lo : ktok_lo;
  const short* Bhi = isQ ? wqT_hi : wkT_hi;
  const short* Blo = isQ ? wqT_lo : wkT_lo;
  short* outp = isQ ? q_split : k_split;

  // regions (shorts): Ahi[0,2048) Alo[2048,4096) Bhi[4096,8192) Blo[8192,12288)
  __shared__ __attribute__((aligned(16))) short sm[2][12288];  // 48KB dbuf

  int tid = threadIdx.x, w = tid >> 6, lane = tid & 63, g = lane >> 4, li = lane & 15;
  int mb = blockIdx.y * 64, nb = blockIdx.x * 128;
  int wm = (w >> 1) * 32, wn = (w & 1) * 64;

  f32x4 acc[2][4] = {};

  auto STAGE = [&](int kb, int buf) {
    {
      int off = tid * 16;
      int row = off >> 6, ss = ((off >> 4) & 3) ^ ((row >> 1) & 3);
      size_t src = (size_t)(mb + row) * 1024 + kb + ss * 8;
      g2lds16(Ahi + src, (char*)&sm[buf][0] + w * 1024);
      g2lds16(Alo + src, (char*)&sm[buf][2048] + w * 1024);
    }
#pragma unroll
    for (int i = 0; i < 2; i++) {
      int off = i * 4096 + tid * 16;
      int row = off >> 6, ss = ((off >> 4) & 3) ^ ((row >> 1) & 3);
      size_t src = (size_t)(nb + row) * 1024 + kb + ss * 8;
      g2lds16(Bhi + src, (char*)&sm[buf][4096] + i * 4096 + w * 1024);
      g2lds16(Blo + src, (char*)&sm[buf][8192] + i * 4096 + w * 1024);
    }
  };

  STAGE(0, 0);
  __syncthreads();
  for (int kb = 0; kb < 1024; kb += 32) {
    int cur = (kb >> 5) & 1;
    if (kb + 32 < 1024) STAGE(kb + 32, cur ^ 1);
    bf16x8 af[2][2], bf[4][2];
#pragma unroll
    for (int f = 0; f < 2; f++) {
      int ra = wm + f * 16 + li, sa = g ^ ((ra >> 1) & 3);
      af[f][0] = *(const bf16x8*)&sm[cur][ra * 32 + sa * 8];
      af[f][1] = *(const bf16x8*)&sm[cur][2048 + ra * 32 + sa * 8];
    }
#pragma unroll
    for (int f = 0; f < 4; f++) {
      int rb = wn + f * 16 + li, sb = g ^ ((rb >> 1) & 3);
      bf[f][0] = *(const bf16x8*)&sm[cur][4096 + rb * 32 + sb * 8];
      bf[f][1] = *(const bf16x8*)&sm[cur][8192 + rb * 32 + sb * 8];
    }
#pragma unroll
    for (int mf = 0; mf < 2; mf++)
#pragma unroll
      for (int nf = 0; nf < 4; nf++) {
        acc[mf][nf] = MFMA_BF16(af[mf][0], bf[nf][0], acc[mf][nf]);
        acc[mf][nf] = MFMA_BF16(af[mf][0], bf[nf][1], acc[mf][nf]);
        acc[mf][nf] = MFMA_BF16(af[mf][1], bf[nf][0], acc[mf][nf]);
      }
    __syncthreads();
  }
#pragma unroll
  for (int mf = 0; mf < 2; mf++)
#pragma unroll
    for (int nf = 0; nf < 4; nf++)
#pragma unroll
      for (int r = 0; r < 4; r++) {
        int m = mb + wm + mf * 16 + 4 * g + r;
        int n = nb + wn + nf * 16 + li;
        float v = acc[mf][nf][r];
        if (isQ) v += bias[n];
        short hi = f32_bf16(v);
        short lo = f32_bf16(v - bf16_f32(hi));
        size_t base = ((size_t)((m >> 11) * 8 + (n >> 6)) * 2048 + (m & 2047)) * 128;
        outp[base + (n & 63)] = hi;
        outp[base + 64 + (n & 63)] = lo;
      }
}

// --------------------------- fp16 kv GEMM (writes kv k-blocked) -------------
// M=4096(key rows) K=1024(t) N=2048(h,c). Tile 64x128. 4 blocks/CU.
// out kvT[bh][kt=64][c=256][k=32] f16.
__global__ __launch_bounds__(256, 4) void kv_gemm(const f16* __restrict__ A,
                                                  const f16* __restrict__ Bm,
                                                  f16* __restrict__ kvT) {
  __shared__ __attribute__((aligned(16))) f16 sm[2][6144];  // A 2048 + B 4096, 24KB
  int tid = threadIdx.x, w = tid >> 6, lane = tid & 63, g = lane >> 4, li = lane & 15;
  int mb = blockIdx.y * 64, nb = blockIdx.x * 128;
  int wm = (w >> 1) * 32, wn = (w & 1) * 64;
  f32x4 acc[2][4] = {};

  auto STAGE = [&](int kb, int buf) {
    {
      int off = tid * 16;
      int row = off >> 6, ss = ((off >> 4) & 3) ^ ((row >> 1) & 3);
      g2lds16(A + (size_t)(mb + row) * 1024 + kb + ss * 8, (char*)&sm[buf][0] + w * 1024);
    }
#pragma unroll
    for (int i = 0; i < 2; i++) {
      int off = i * 4096 + tid * 16;
      int row = off >> 6, ss = ((off >> 4) & 3) ^ ((row >> 1) & 3);
      g2lds16(Bm + (size_t)(nb + row) * 1024 + kb + ss * 8,
              (char*)&sm[buf][2048] + i * 4096 + w * 1024);
    }
  };

  STAGE(0, 0);
  __syncthreads();
  for (int kb = 0; kb < 1024; kb += 32) {
    int cur = (kb >> 5) & 1;
    if (kb + 32 < 1024) STAGE(kb + 32, cur ^ 1);
    f16x8 af[2], bf[4];
#pragma unroll
    for (int f = 0; f < 2; f++) {
      int ra = wm + f * 16 + li, sa = g ^ ((ra >> 1) & 3);
      af[f] = *(const f16x8*)&sm[cur][ra * 32 + sa * 8];
    }
#pragma unroll
    for (int f = 0; f < 4; f++) {
      int rb = wn + f * 16 + li, sb = g ^ ((rb >> 1) & 3);
      bf[f] = *(const f16x8*)&sm[cur][2048 + rb * 32 + sb * 8];
    }
#pragma unroll
    for (int mf = 0; mf < 2; mf++)
#pragma unroll
      for (int nf = 0; nf < 4; nf++)
        acc[mf][nf] = MFMA_F16(af[mf], bf[nf], acc[mf][nf]);
    __syncthreads();
  }
#pragma unroll
  for (int mf = 0; mf < 2; mf++)
#pragma unroll
    for (int nf = 0; nf < 4; nf++) {
      int m = mb + wm + mf * 16 + 4 * g;  // 4 consecutive keys in regs 0..3
      int n = nb + wn + nf * 16 + li;     // (h<<8)|c
      f16x4 v = {(f16)acc[mf][nf][0], (f16)acc[mf][nf][1], (f16)acc[mf][nf][2],
                 (f16)acc[mf][nf][3]};
      int bh = (m >> 11) * 8 + (n >> 8);
      size_t o = (size_t)bh * 524288 + (size_t)((m & 2047) >> 5) * 8192 +
                 (size_t)(n & 255) * 32 + (m & 31);
      *(f16x4*)(kvT + o) = v;
    }
}

// --------------------------- flash swishmax attention (split-K) --------------
// grid 1024 = 2 key-halves x 16 bh x 32 qb, 4 waves, KVBLK=64, 16 iters, ONE
// barrier per iter. Identical r10 inner structure; each block covers keys
// [kb2*1024, +1024) and writes a partial P_b (same epilogue math) + per-q
// L_b = l_run*sfix, M_b = m_true for the combine kernel. 49KB LDS -> 3
// blocks/CU (vs 2 before the split).
__global__ __launch_bounds__(256, 3) void flash_attn(const short* __restrict__ q_split,
                                                     const short* __restrict__ k_split,
                                                     const f16* __restrict__ kvT,
                                                     f16* __restrict__ P0,
                                                     f16* __restrict__ P1,
                                                     float* __restrict__ Lm,
                                                     float* __restrict__ Mm) {
  __shared__ __attribute__((aligned(16))) short k_lds[2][8192];  // [64k][256B] 2x16KB
  __shared__ __attribute__((aligned(16))) f16 p_lds[2][4096];    // [64q][128B] 2x8KB
  __shared__ float sc_lds[2][4][16];  // [par][owner wave][q%16] rescale factors
  __shared__ float fix_lds[64];

  const int bid = blockIdx.x;
  const int kb2 = bid & 1;            // key half
  const int r_ = bid >> 1;
  const int bh = ((r_ & 7) << 1) + ((r_ >> 3) & 1);
  const int qb = r_ >> 4;
  const int tid = threadIdx.x;
  const int w = tid >> 6, lane = tid & 63, g = lane >> 4, li = lane & 15;

  // Q fragments (persist): B-operand, lane holds its q-row's a-slice
  const short* qrow = q_split + ((size_t)bh * 2048 + qb * 64 + w * 16 + li) * 128;
  bf16x8 qf[2][2];
#pragma unroll
  for (int ach = 0; ach < 2; ach++)
#pragma unroll
    for (int hl = 0; hl < 2; hl++)
      qf[ach][hl] = *(const bf16x8*)(qrow + hl * 64 + ach * 32 + g * 8);

  const short* kbase = k_split + (size_t)bh * 262144 + (size_t)kb2 * 131072;
  // wave-private kv base: c-quadrant w, A-frag (c row = ct*16+li, k = g*8+j)
  const f16* kvbase = kvT + (size_t)bh * 524288 + (size_t)kb2 * 262144 +
                      (size_t)w * 2048 + li * 32 + g * 8;

  float m_cur = -INFINITY, m_true = -INFINITY, l_run = 0.f;
  f32x4 acc[4][4] = {};  // [ct][qt]
  f16x8 kvf[2][4];       // [k-half][ct] A-frags for this wave's c-quadrant

  auto STAGE_K = [&](int t, int buf) {
    // K tile [64 keys][256B rows, 16 slots of 16B], read-swz slot^(row&7)
#pragma unroll
    for (int i = 0; i < 4; i++) {
      int off = (w * 4 + i) * 1024 + lane * 16;
      int row = off >> 8;
      int ss = ((off >> 4) & 15) ^ (row & 7);
      g2lds16(kbase + t * 8192 + row * 128 + ss * 8,
              (char*)k_lds[buf] + (w * 4 + i) * 1024);
    }
  };

  auto LOADKV = [&](int t) {
    // kvT half: kt32-local {2t, 2t+1}
#pragma unroll
    for (int h = 0; h < 2; h++) {
      const f16* p = kvbase + (size_t)(2 * t + h) * 8192;
#pragma unroll
      for (int ct = 0; ct < 4; ct++) kvf[h][ct] = *(const f16x8*)(p + ct * 512);
    }
  };

  // QK^T + online swishmax for 64-key tile; K from k_lds[buf]; publishes P^T
  // and per-q rescale factor sc into parity buf.
  auto QKSM = [&](int buf) {
    f32x4 s[4] = {};
    __builtin_amdgcn_s_setprio(1);
#pragma unroll
    for (int kc = 0; kc < 4; kc++) {
      const int r = kc * 16 + li;
#pragma unroll
      for (int ach = 0; ach < 2; ach++) {
        int sh = (ach * 4 + g) ^ (r & 7);
        int sl = (8 + ach * 4 + g) ^ (r & 7);
        bf16x8 khi = *(const bf16x8*)((const char*)k_lds[buf] + r * 256 + sh * 16);
        bf16x8 klo = *(const bf16x8*)((const char*)k_lds[buf] + r * 256 + sl * 16);
        s[kc] = MFMA_BF16(khi, qf[ach][0], s[kc]);
        s[kc] = MFMA_BF16(khi, qf[ach][1], s[kc]);
        s[kc] = MFMA_BF16(klo, qf[ach][0], s[kc]);
      }
    }
    __builtin_amdgcn_s_setprio(0);

    // online swishmax; per-lane state is per-q (q = w*16+li after reductions)
    float tmax = -INFINITY;
#pragma unroll
    for (int kc = 0; kc < 4; kc++)
      tmax = fmaxf(tmax, fmaxf(fmaxf(s[kc][0], s[kc][1]), fmaxf(s[kc][2], s[kc][3])));
    tmax = fmaxf(tmax, __shfl_xor(tmax, 16));
    tmax = fmaxf(tmax, __shfl_xor(tmax, 32));
    m_true = fmaxf(m_true, tmax);
    float sc = 1.0f;
    if (__any(tmax > m_cur + 4.0f)) {  // deferred rescale; P <= ~117*e^4 < f16 max
      float mn = fmaxf(m_cur, tmax);
      sc = __expf(m_cur - mn);  // per-q factor (1.0 where tmax <= m_cur)
      l_run *= sc;
      m_cur = mn;
    }
    // publish per-q rescale factor for acc owners (all waves hold acc for q)
    if (g == 0) sc_lds[buf][w][li] = sc;

    float ls = 0.f;
    float pv[16];
#pragma unroll
    for (int kc = 0; kc < 4; kc++)
#pragma unroll
      for (int r2 = 0; r2 < 4; r2++) {
        float sv = s[kc][r2];
        float e = sv * __expf(sv - m_cur);
        pv[kc * 4 + r2] = e;
        ls += fabsf(e);
      }
    ls += __shfl_xor(ls, 16);
    ls += __shfl_xor(ls, 32);
    l_run += ls;

    // write P^T[q][64k] (f16), 128B rows, q-row XOR swizzle ((q&7)<<4)
#pragma unroll
    for (int kc = 0; kc < 4; kc++) {
      f16x4 p4 = {(f16)pv[kc * 4], (f16)pv[kc * 4 + 1], (f16)pv[kc * 4 + 2],
                  (f16)pv[kc * 4 + 3]};
      int wb = ((w * 16 + li) * 128 + kc * 32 + g * 8) ^ ((li & 7) << 4);
      *(f16x4*)((char*)p_lds[buf] + wb) = p4;
    }
  };

  // prologue: K(0), K(1) staged; tile 0's P/sc published into parity 0
  STAGE_K(0, 0);
  STAGE_K(1, 1);
  __syncthreads();
  QKSM(0);

#pragma unroll 2
  for (int t = 0; t < 16; t++) {
    const int cur = t & 1;
    // P(t)/sc(t) visible to all waves; K(t+1) stage landed (vmcnt drained).
    __syncthreads();
    LOADKV(t);  // global->reg, wave-private; consumed in PV(t) below
    if (t < 14) STAGE_K(t + 2, cur);
    if (t < 15) QKSM(cur ^ 1);  // tile t+1 -> parity cur^1

    // apply q-owners' rescale factors for tile t (rare after warmup)
#pragma unroll
    for (int qt = 0; qt < 4; qt++) {
      float scq = sc_lds[cur][qt][li];
      if (__any(scq != 1.0f)) {
#pragma unroll
        for (int ct = 0; ct < 4; ct++) acc[ct][qt] *= scq;
      }
    }

    // PV(t): acc[c-quadrant][all q] += kv[c][k] * P^T[k][q]
    __builtin_amdgcn_s_setprio(1);
#pragma unroll
    for (int qt = 0; qt < 4; qt++) {
#pragma unroll
      for (int h = 0; h < 2; h++) {
        int rb = ((qt * 16 + li) * 128 + h * 64 + g * 16) ^ ((li & 7) << 4);
        f16x8 pf = *(const f16x8*)((const char*)p_lds[cur] + rb);
#pragma unroll
        for (int ct = 0; ct < 4; ct++)
          acc[ct][qt] = MFMA_F16(kvf[h][ct], pf, acc[ct][qt]);
      }
    }
    __builtin_amdgcn_s_setprio(0);
  }

  // block epilogue: same math as before (as-if-alone output), plus L/M scalars
  float sfix = __expf(m_cur - m_true);
  float invd = sfix / (l_run * sfix + 1.0f);
  __syncthreads();
  if (g == 0) {
    fix_lds[w * 16 + li] = invd;
    int qg = qb * 64 + w * 16 + li;
    Lm[(size_t)kb2 * 32768 + bh * 2048 + qg] = l_run * sfix;
    Mm[(size_t)kb2 * 32768 + bh * 2048 + qg] = m_true;
  }
  __syncthreads();
  f16* Pb = kb2 ? P1 : P0;
#pragma unroll
  for (int qt = 0; qt < 4; qt++) {
    float iv = fix_lds[qt * 16 + li];
    f16* orow = Pb + ((size_t)(bh >> 3) * 2048 + qb * 64 + qt * 16 + li) * 2048 +
                (bh & 7) * 256 + w * 64 + g * 4;
#pragma unroll
    for (int ct = 0; ct < 4; ct++) {
      f16x4 v = {(f16)(acc[ct][qt][0] * iv), (f16)(acc[ct][qt][1] * iv),
                 (f16)(acc[ct][qt][2] * iv), (f16)(acc[ct][qt][3] * iv)};
      *(f16x4*)(orow + ct * 16) = v;
    }
  }
}

// --------------------------- split-K combine ---------------------------------
// out = (P0*(L0+1)*w0 + P1*(L1+1)*w1) / (L0*w0 + L1*w1 + 1), w_b=e^{M_b-M}.
// In-place over P0 (becomes vs_c). Elementwise, HBM-bound (~48MB).
__global__ __launch_bounds__(256) void combine_halves(const f16* __restrict__ p1,
                                                      f16* __restrict__ p0io,
                                                      const float* __restrict__ Lm,
                                                      const float* __restrict__ Mm) {
  size_t i = (size_t)blockIdx.x * 256 + threadIdx.x;  // 1M threads x 8 f16
  size_t lin8 = i * 8;
  int batch = (int)(lin8 >> 22);           // / (2048*2048)
  int q = (int)((lin8 >> 11) & 2047);
  int h = (int)((lin8 & 2047) >> 8);
  int s = (batch * 8 + h) * 2048 + q;
  float L0 = Lm[s], L1 = Lm[32768 + s];
  float M0 = Mm[s], M1 = Mm[32768 + s];
  float M = fmaxf(M0, M1);
  float w0 = __expf(M0 - M), w1 = __expf(M1 - M);
  float a0 = (L0 + 1.0f) * w0, a1 = (L1 + 1.0f) * w1;
  float invd = 1.0f / (L0 * w0 + L1 * w1 + 1.0f);
  f16x8 v0 = *(const f16x8*)(p0io + lin8);
  f16x8 v1 = *(const f16x8*)(p1 + lin8);
  f16x8 o;
#pragma unroll
  for (int e = 0; e < 8; e++)
    o[e] = (f16)(((float)v0[e] * a0 + (float)v1[e] * a1) * invd);
  *(f16x8*)(p0io + lin8) = o;
}

// --------------------------- fp16 final GEMM (head-sum in K) -----------------
// M=4096(b,q) K=2048(h,c) N=1024(t). Tile 64x128. out fp32.  [r10 version]
__global__ __launch_bounds__(256, 4) void final_gemm(const f16* __restrict__ A,
                                                     const f16* __restrict__ Bm,
                                                     float* __restrict__ outp) {
  __shared__ __attribute__((aligned(16))) f16 sm[2][6144];  // 24KB dbuf
  int tid = threadIdx.x, w = tid >> 6, lane = tid & 63, g = lane >> 4, li = lane & 15;
  int mb = blockIdx.y * 64, nb = blockIdx.x * 128;
  int wm = (w >> 1) * 32, wn = (w & 1) * 64;
  f32x4 acc[2][4] = {};

  auto STAGE = [&](int kb, int buf) {
    {
      int off = tid * 16;
      int row = off >> 6, ss = ((off >> 4) & 3) ^ ((row >> 1) & 3);
      g2lds16(A + (size_t)(mb + row) * 2048 + kb + ss * 8, (char*)&sm[buf][0] + w * 1024);
    }
#pragma unroll
    for (int i = 0; i < 2; i++) {
      int off = i * 4096 + tid * 16;
      int row = off >> 6, ss = ((off >> 4) & 3) ^ ((row >> 1) & 3);
      g2lds16(Bm + (size_t)(nb + row) * 2048 + kb + ss * 8,
              (char*)&sm[buf][2048] + i * 4096 + w * 1024);
    }
  };

  STAGE(0, 0);
  __syncthreads();
  for (int kb = 0; kb < 2048; kb += 32) {
    int cur = (kb >> 5) & 1;
    if (kb + 32 < 2048) STAGE(kb + 32, cur ^ 1);
    f16x8 af[2], bf[4];
#pragma unroll
    for (int f = 0; f < 2; f++) {
      int ra = wm + f * 16 + li, sa = g ^ ((ra >> 1) & 3);
      af[f] = *(const f16x8*)&sm[cur][ra * 32 + sa * 8];
    }
#pragma unroll
    for (int f = 0; f < 4; f++) {
      int rb = wn + f * 16 + li, sb = g ^ ((rb >> 1) & 3);
      bf[f] = *(const f16x8*)&sm[cur][2048 + rb * 32 + sb * 8];
    }
#pragma unroll
    for (int mf = 0; mf < 2; mf++)
#pragma unroll
      for (int nf = 0; nf < 4; nf++)
        acc[mf][nf] = MFMA_F16(af[mf], bf[nf], acc[mf][nf]);
    __syncthreads();
  }
#pragma unroll
  for (int mf = 0; mf < 2; mf++)
#pragma unroll
    for (int nf = 0; nf < 4; nf++)
#pragma unroll
      for (int r = 0; r < 4; r++) {
        int m = mb + wm + mf * 16 + 4 * g + r;
        int n = nb + wn + nf * 16 + li;
        outp[(size_t)m * 1024 + n] = acc[mf][nf][r];
      }
}

// ---------------------------------------------------------------------------
extern "C" void kernel_launch(void* const* d_in, const int* in_sizes, int n_in,
                              void* d_out, int out_size, void* d_ws, size_t ws_size,
                              hipStream_t stream) {
  (void)in_sizes; (void)n_in; (void)out_size; (void)ws_size;
  const float* qtok = (const float*)d_in[0];  // [2,2048,1024]
  const float* ktok = (const float*)d_in[1];  // [2,2048,1024]
  const float* kdw = (const float*)d_in[2];   // [8,1024,64]
  const float* qdw = (const float*)d_in[3];   // [8,1024,64]
  const float* qdb = (const float*)d_in[4];   // [8,1,64]
  const float* vdw = (const float*)d_in[5];   // [8,1024,256]
  const float* vup = (const float*)d_in[6];   // [8,256,1024]

  char* ws = (char*)d_ws;
  size_t off = 0;
  auto take = [&](size_t n) { void* p = ws + off; off += (n + 255) & ~(size_t)255; return p; };

  short* qtok_hi = (short*)take(8u << 20);  // @0   [4096][1024] bf16
  short* qtok_lo = (short*)take(8u << 20);  // @8M
  short* ktok_hi = (short*)take(8u << 20);  // @16M
  short* ktok_lo = (short*)take(8u << 20);  // @24M
  f16* ktok_f = (f16*)take(8u << 20);       // @32M [4096][1024] f16
  short* wqT_hi = (short*)take(1u << 20);   // @40M [512][1024]
  short* wqT_lo = (short*)take(1u << 20);   // @41M
  short* wkT_hi = (short*)take(1u << 20);   // @42M
  short* wkT_lo = (short*)take(1u << 20);   // @43M
  f16* vdT = (f16*)take(4u << 20);          // @44M [2048][1024] f16 (Wv_down^T)
  f16* vuT = (f16*)take(4u << 20);          // @48M [1024][2048] f16 (Wv_up^T)
  short* q_split = (short*)take(8u << 20);  // @52M [16][2048][128] bf16 hi|lo
  short* k_split = (short*)take(8u << 20);  // @60M
  float* Lm = (float*)take(256u << 10);     // @68M [2][16 bh][2048 q]
  float* Mm = (float*)take(256u << 10);     // [2][16 bh][2048 q]
  // Aliased scratch (stream-ordered safe):
  f16* kvT = (f16*)(void*)ktok_hi;   // 16MB @16M: dead {k}tok_{hi,lo} after proj
  f16* vs_c = (f16*)(void*)qtok_hi;  // 16MB @0:   dead {q}tok_{hi,lo} after proj
  f16* P1 = (f16*)(void*)ktok_f;     // 16MB @32M: ktok_f+weights+vdT dead after kv/proj

  ew_split2<<<8192, 256, 0, stream>>>(qtok, ktok, qtok_hi, qtok_lo, ktok_hi,
                                      ktok_lo, ktok_f);
  transpose_all<<<1280, 256, 0, stream>>>(qdw, kdw, vdw, vup, wqT_hi, wqT_lo,
                                          wkT_hi, wkT_lo, vdT, vuT);
  proj_gemm<<<dim3(4, 64, 2), 256, 0, stream>>>(qtok_hi, qtok_lo, ktok_hi, ktok_lo,
                                                wqT_hi, wqT_lo, wkT_hi, wkT_lo, qdb,
                                                q_split, k_split);
  kv_gemm<<<dim3(16, 64), 256, 0, stream>>>(ktok_f, vdT, kvT);
  flash_attn<<<1024, 256, 0, stream>>>(q_split, k_split, kvT, vs_c, P1, Lm, Mm);
  combine_halves<<<4096, 256, 0, stream>>>(P1, vs_c, Lm, Mm);
  final_gemm<<<dim3(8, 64), 256, 0, stream>>>(vs_c, vuT, (float*)d_out);
}